// Round 3
// baseline (187.473 us; speedup 1.0000x reference)
//
#include <hip/hip_runtime.h>
#include <hip/hip_bf16.h>

#define DDIM 256
#define NROWS 8192

typedef __attribute__((ext_vector_type(8))) __bf16 bf16x8;
typedef __attribute__((ext_vector_type(4))) float floatx4;

// Kernel 1: L2-normalize rows of U and P to bf16, compute pos_sim, zero the
// rowsum accumulator and the output scalar. One wave per row.
__global__ __launch_bounds__(256) void normalize_kernel(
    const float* __restrict__ U, const float* __restrict__ P,
    unsigned short* __restrict__ Un, unsigned short* __restrict__ Pn,
    float* __restrict__ possim, float* __restrict__ rowsum,
    float* __restrict__ out)
{
    if (blockIdx.x == 0 && threadIdx.x == 0) out[0] = 0.0f;
    const int lane = threadIdx.x & 63;
    const int row  = blockIdx.x * 4 + (threadIdx.x >> 6);
    const size_t base = (size_t)row * DDIM + lane * 4;
    const float4 u4 = *(const float4*)(U + base);
    const float4 p4 = *(const float4*)(P + base);
    float su = u4.x*u4.x + u4.y*u4.y + u4.z*u4.z + u4.w*u4.w;
    float sp = p4.x*p4.x + p4.y*p4.y + p4.z*p4.z + p4.w*p4.w;
    float up = u4.x*p4.x + u4.y*p4.y + u4.z*p4.z + u4.w*p4.w;
    #pragma unroll
    for (int d = 1; d < 64; d <<= 1) {
        su += __shfl_xor(su, d);
        sp += __shfl_xor(sp, d);
        up += __shfl_xor(up, d);
    }
    const float iu = rsqrtf(fmaxf(su, 1e-24f));
    const float ip = rsqrtf(fmaxf(sp, 1e-24f));
    if (lane == 0) {
        possim[row] = up * iu * ip;
        rowsum[row] = 0.0f;
    }
    union { ushort4 s4; __hip_bfloat16 h[4]; } cu, cp;
    cu.h[0] = __float2bfloat16(u4.x * iu); cu.h[1] = __float2bfloat16(u4.y * iu);
    cu.h[2] = __float2bfloat16(u4.z * iu); cu.h[3] = __float2bfloat16(u4.w * iu);
    cp.h[0] = __float2bfloat16(p4.x * ip); cp.h[1] = __float2bfloat16(p4.y * ip);
    cp.h[2] = __float2bfloat16(p4.z * ip); cp.h[3] = __float2bfloat16(p4.w * ip);
    *(ushort4*)(Un + base) = cu.s4;
    *(ushort4*)(Pn + base) = cp.s4;
}

// Kernel 2: 128x128 tile of sim = Un * Pn^T per block, NO LDS, no barriers.
// MFMA 16x16x32 A/B fragments are loaded directly from row-major global as
// aligned dwordx4: lane (m = lane&15, q = lane>>4) reads
//   A[rowbase + t*16 + m][kc*32 + q*8 .. +7]   (16 B contiguous, L2-resident)
// Waves free-run the K loop with compiler-scheduled vmcnt(N) waits -> the
// load latency is hidden by MFMAs of adjacent K steps, no phase alignment.
// Cost: 2x read amplification (every fragment read per-wave), ~1.07 GB from
// L2 total. Patch swizzle (16x16 tiles) keeps per-XCD working set ~2 MB.
__global__ __launch_bounds__(256) void sim_exp_rowsum(
    const unsigned short* __restrict__ Un,
    const unsigned short* __restrict__ Pn,
    float* __restrict__ rowsum)
{
    const int tid  = threadIdx.x;
    const int lane = tid & 63;
    const int wv   = tid >> 6;
    const int wr   = wv >> 1, wc = wv & 1;
    const int m = lane & 15;
    const int q = lane >> 4;

    // patch swizzle: 4096 tiles = 4x4 patches of 16x16 tiles
    const int patch = blockIdx.x >> 8;       // 0..15
    const int pin   = blockIdx.x & 255;
    const int ry    = (patch >> 2) * 16 + (pin >> 4);   // row tile 0..63
    const int cx    = (patch & 3) * 16 + (pin & 15);    // col tile 0..63

    const int rowbase = ry * 128 + wr * 64;
    const int colbase = cx * 128 + wc * 64;

    // per-lane fragment base pointers (16 B aligned; row stride 512 B)
    const unsigned short* Abase = Un + (size_t)(rowbase + m) * DDIM + q * 8;
    const unsigned short* Bbase = Pn + (size_t)(colbase + m) * DDIM + q * 8;

    floatx4 acc[4][4];
    #pragma unroll
    for (int t = 0; t < 4; ++t)
        #pragma unroll
        for (int u = 0; u < 4; ++u)
            acc[t][u] = {0.0f, 0.0f, 0.0f, 0.0f};

    #pragma unroll
    for (int ks = 0; ks < 8; ++ks) {         // K = 256 = 8 x 32
        bf16x8 af[4], bfr[4];
        #pragma unroll
        for (int t = 0; t < 4; ++t)
            af[t]  = *(const bf16x8*)(Abase + (size_t)t * 16 * DDIM + ks * 32);
        #pragma unroll
        for (int u = 0; u < 4; ++u)
            bfr[u] = *(const bf16x8*)(Bbase + (size_t)u * 16 * DDIM + ks * 32);
        #pragma unroll
        for (int t = 0; t < 4; ++t)
            #pragma unroll
            for (int u = 0; u < 4; ++u)
                acc[t][u] = __builtin_amdgcn_mfma_f32_16x16x32_bf16(
                    af[t], bfr[u], acc[t][u], 0, 0, 0);
    }

    // Epilogue: C/D layout col = lane&15, row = (lane>>4)*4 + reg.
    // exp(5*dot); sum this wave's 64 columns (4 in-lane + 16-lane shuffle),
    // one atomicAdd per row per wave.
    #pragma unroll
    for (int t = 0; t < 4; ++t) {
        #pragma unroll
        for (int r = 0; r < 4; ++r) {
            float s = __expf(5.0f * acc[t][0][r]) + __expf(5.0f * acc[t][1][r])
                    + __expf(5.0f * acc[t][2][r]) + __expf(5.0f * acc[t][3][r]);
            s += __shfl_xor(s, 1);
            s += __shfl_xor(s, 2);
            s += __shfl_xor(s, 4);
            s += __shfl_xor(s, 8);
            if (m == 0) {
                const int grow = rowbase + t * 16 + q * 4 + r;
                atomicAdd(&rowsum[grow], s);
            }
        }
    }
}

// Kernel 3: loss = mean_i( log(rowsum_i) - 5 * possim_i ). 32 blocks, one
// element per thread, block-reduce, atomicAdd into out (zeroed by kernel 1).
__global__ __launch_bounds__(256) void finalize_kernel(
    const float* __restrict__ rowsum, const float* __restrict__ possim,
    float* __restrict__ out)
{
    const int i = blockIdx.x * 256 + threadIdx.x;
    float acc = __logf(rowsum[i]) - 5.0f * possim[i];
    #pragma unroll
    for (int d = 1; d < 64; d <<= 1) acc += __shfl_xor(acc, d);
    __shared__ float wsum[4];
    if ((threadIdx.x & 63) == 0) wsum[threadIdx.x >> 6] = acc;
    __syncthreads();
    if (threadIdx.x == 0)
        atomicAdd(out, (wsum[0] + wsum[1] + wsum[2] + wsum[3]) * (1.0f / (float)NROWS));
}

extern "C" void kernel_launch(void* const* d_in, const int* in_sizes, int n_in,
                              void* d_out, int out_size, void* d_ws, size_t ws_size,
                              hipStream_t stream) {
    const float* U = (const float*)d_in[0];
    const float* P = (const float*)d_in[1];
    float* out = (float*)d_out;
    char* ws = (char*)d_ws;
    // ws layout: Un bf16 (4 MB) | Pn bf16 (4 MB) | rowsum f32 (32 KB) | possim f32 (32 KB)
    unsigned short* Un = (unsigned short*)ws;
    unsigned short* Pn = (unsigned short*)(ws + 4194304);
    float* rowsum = (float*)(ws + 8388608);
    float* possim = (float*)(ws + 8388608 + 32768);

    normalize_kernel<<<NROWS / 4, 256, 0, stream>>>(U, P, Un, Pn, possim, rowsum, out);
    sim_exp_rowsum<<<4096, 256, 0, stream>>>(Un, Pn, rowsum);
    finalize_kernel<<<NROWS / 256, 256, 0, stream>>>(rowsum, possim, out);
}

// Round 4
// 144.612 us; speedup vs baseline: 1.2964x; 1.2964x over previous
//
#include <hip/hip_runtime.h>
#include <hip/hip_bf16.h>

#define DDIM 256
#define NROWS 8192

typedef __attribute__((ext_vector_type(8))) __bf16 bf16x8;
typedef __attribute__((ext_vector_type(4))) float floatx4;

// async global->LDS, 16B per lane. LDS dest is wave-uniform base + lane*16.
__device__ __forceinline__ void async16(const void* g, void* l) {
    __builtin_amdgcn_global_load_lds(
        (const __attribute__((address_space(1))) unsigned int*)g,
        (__attribute__((address_space(3))) unsigned int*)l,
        16, 0, 0);
}

// Stage rows_per_wave rows (full K=256, 512 B/row) per wave into LDS at l,
// linear layout with granule swizzle: stored granule position g holds logical
// granule g ^ (row&7). One async16 covers 2 rows (64 lanes x 16 B).
// Global access stays contiguous (permutation is within a row's 8-granule
// blocks); frag reads then xor by (m&7) -> 2-way bank aliasing only (free).
__device__ __forceinline__ void stage_rows(const unsigned short* __restrict__ g,
                                           unsigned short* l,
                                           int wv, int lane,
                                           int rows_per_wave, int ninstr)
{
    const int lrow = lane >> 5;       // 0..1
    const int gcol = lane & 31;       // granule 0..31
    const int r0 = wv * rows_per_wave;
    for (int j = 0; j < ninstr; ++j) {
        const int rb = r0 + j * 2;
        const int r  = rb + lrow;
        const int gg = gcol ^ (r & 7);
        async16(g + (size_t)r * DDIM + gg * 8, l + (size_t)rb * DDIM);
    }
}

__device__ __forceinline__ bf16x8 frag(const unsigned short* base, int row,
                                       int ks, int q, int m)
{
    return *(const bf16x8*)&base[(size_t)row * DDIM
                                 + (((ks * 4 + q) ^ (m & 7)) * 8)];
}

// Kernel 1: L2-normalize rows of U and P to bf16, compute pos_sim, zero
// rowsum / out / ticket counter. One wave per row.
__global__ __launch_bounds__(256) void normalize_kernel(
    const float* __restrict__ U, const float* __restrict__ P,
    unsigned short* __restrict__ Un, unsigned short* __restrict__ Pn,
    float* __restrict__ possim, float* __restrict__ rowsum,
    float* __restrict__ out, int* __restrict__ counter)
{
    if (blockIdx.x == 0 && threadIdx.x == 0) { out[0] = 0.0f; counter[0] = 0; }
    const int lane = threadIdx.x & 63;
    const int row  = blockIdx.x * 4 + (threadIdx.x >> 6);
    const size_t base = (size_t)row * DDIM + lane * 4;
    const float4 u4 = *(const float4*)(U + base);
    const float4 p4 = *(const float4*)(P + base);
    float su = u4.x*u4.x + u4.y*u4.y + u4.z*u4.z + u4.w*u4.w;
    float sp = p4.x*p4.x + p4.y*p4.y + p4.z*p4.z + p4.w*p4.w;
    float up = u4.x*p4.x + u4.y*p4.y + u4.z*p4.z + u4.w*p4.w;
    #pragma unroll
    for (int d = 1; d < 64; d <<= 1) {
        su += __shfl_xor(su, d);
        sp += __shfl_xor(sp, d);
        up += __shfl_xor(up, d);
    }
    const float iu = rsqrtf(fmaxf(su, 1e-24f));
    const float ip = rsqrtf(fmaxf(sp, 1e-24f));
    if (lane == 0) {
        possim[row] = up * iu * ip;
        rowsum[row] = 0.0f;
    }
    union { ushort4 s4; __hip_bfloat16 h[4]; } cu, cp;
    cu.h[0] = __float2bfloat16(u4.x * iu); cu.h[1] = __float2bfloat16(u4.y * iu);
    cu.h[2] = __float2bfloat16(u4.z * iu); cu.h[3] = __float2bfloat16(u4.w * iu);
    cp.h[0] = __float2bfloat16(p4.x * ip); cp.h[1] = __float2bfloat16(p4.y * ip);
    cp.h[2] = __float2bfloat16(p4.z * ip); cp.h[3] = __float2bfloat16(p4.w * ip);
    *(ushort4*)(Un + base) = cu.s4;
    *(ushort4*)(Pn + base) = cp.s4;
}

// Kernel 2: persistent-A GEMM + exp-rowsum + fused finalize.
// 512 blocks (2/CU, 64 KB LDS), 4 waves (2x2: wr rows, wc cols).
// Block = stripe (128 rows) x octant (1024 cols = 16 tiles of 64).
// A-stripe staged to LDS once, A-frags held in registers (32 x bf16x8);
// B double-buffered 2x32 KB: loads issued right after the barrier, consumed
// at the NEXT barrier -> full compute phase (~1242 cyc) in flight, so the
// barrier's vmcnt(0) drain is cheap. exp partials kept per-lane across all
// 16 iters; one shuffle-reduce + 16 atomics per wave at the end.
__global__ __launch_bounds__(256, 2) void sim_exp_rowsum(
    const unsigned short* __restrict__ Un,
    const unsigned short* __restrict__ Pn,
    float* __restrict__ rowsum,
    const float* __restrict__ possim,
    int* __restrict__ counter,
    float* __restrict__ out)
{
    __shared__ __align__(16) unsigned short lds[32768];   // 64 KB: 2 x 32 KB B bufs; A transient
    __shared__ float ws4[4];
    __shared__ int ticket_s;

    const int tid  = threadIdx.x;
    const int lane = tid & 63;
    const int wv   = tid >> 6;
    const int wr   = wv >> 1, wc = wv & 1;
    const int m = lane & 15;
    const int q = lane >> 4;

    const int stripe = blockIdx.x >> 3;   // 0..63
    const int oct    = blockIdx.x & 7;    // 0..7

    // ---- Prologue: stage A stripe (128 rows), pull A-frags to registers ----
    const unsigned short* Aglob = Un + (size_t)stripe * 128 * DDIM;
    stage_rows(Aglob, lds, wv, lane, 32, 16);
    __syncthreads();

    bf16x8 afr[4][8];
    #pragma unroll
    for (int t = 0; t < 4; ++t)
        #pragma unroll
        for (int ks = 0; ks < 8; ++ks)
            afr[t][ks] = frag(lds, wr * 64 + t * 16 + m, ks, q, m);
    __syncthreads();   // all waves have A in regs; LDS free for B bufs

    // ---- Main loop: 16 col-tiles of 64, B double-buffered ----
    const unsigned short* Bglob = Pn + (size_t)(oct * 1024) * DDIM;
    float rowpart[4][4];
    #pragma unroll
    for (int t = 0; t < 4; ++t)
        #pragma unroll
        for (int r = 0; r < 4; ++r)
            rowpart[t][r] = 0.0f;

    stage_rows(Bglob, lds, wv, lane, 16, 8);   // tile 0 -> buf0

    for (int i = 0; i < 16; ++i) {
        __syncthreads();   // drains B[i] loads (in flight through iter i-1)
        if (i < 15)
            stage_rows(Bglob + (size_t)(i + 1) * 64 * DDIM,
                       lds + ((i + 1) & 1) * 16384, wv, lane, 16, 8);
        const unsigned short* Bp = lds + (i & 1) * 16384;

        floatx4 acc[4][2];
        #pragma unroll
        for (int t = 0; t < 4; ++t) {
            acc[t][0] = {0.0f, 0.0f, 0.0f, 0.0f};
            acc[t][1] = {0.0f, 0.0f, 0.0f, 0.0f};
        }
        #pragma unroll
        for (int ks = 0; ks < 8; ++ks) {
            const bf16x8 b0 = frag(Bp, wc * 32 + m,      ks, q, m);
            const bf16x8 b1 = frag(Bp, wc * 32 + 16 + m, ks, q, m);
            #pragma unroll
            for (int t = 0; t < 4; ++t) {
                acc[t][0] = __builtin_amdgcn_mfma_f32_16x16x32_bf16(
                    afr[t][ks], b0, acc[t][0], 0, 0, 0);
                acc[t][1] = __builtin_amdgcn_mfma_f32_16x16x32_bf16(
                    afr[t][ks], b1, acc[t][1], 0, 0, 0);
            }
        }
        // exp(5*sim) accumulated per-lane; C/D: col = m, row = q*4 + r (+t*16)
        #pragma unroll
        for (int t = 0; t < 4; ++t)
            #pragma unroll
            for (int r = 0; r < 4; ++r)
                rowpart[t][r] += __expf(5.0f * acc[t][0][r])
                               + __expf(5.0f * acc[t][1][r]);
    }

    // ---- Epilogue: reduce 16 column-lanes, one atomic per row per wave ----
    #pragma unroll
    for (int t = 0; t < 4; ++t) {
        #pragma unroll
        for (int r = 0; r < 4; ++r) {
            float s = rowpart[t][r];
            s += __shfl_xor(s, 1);
            s += __shfl_xor(s, 2);
            s += __shfl_xor(s, 4);
            s += __shfl_xor(s, 8);
            if (m == 0) {
                const int grow = stripe * 128 + wr * 64 + t * 16 + q * 4 + r;
                atomicAdd(&rowsum[grow], s);
            }
        }
    }

    // ---- Fused finalize: last block computes the loss ----
    __threadfence();
    __syncthreads();   // vmcnt(0) drain: this block's atomics are visible
    if (tid == 0)
        ticket_s = __hip_atomic_fetch_add(counter, 1, __ATOMIC_ACQ_REL,
                                          __HIP_MEMORY_SCOPE_AGENT);
    __syncthreads();
    if (ticket_s == 511) {
        float part = 0.0f;
        for (int i = tid; i < NROWS; i += 256) {
            const float rs = __hip_atomic_load(&rowsum[i], __ATOMIC_RELAXED,
                                               __HIP_MEMORY_SCOPE_AGENT);
            part += __logf(rs) - 5.0f * possim[i];
        }
        #pragma unroll
        for (int d = 1; d < 64; d <<= 1) part += __shfl_xor(part, d);
        if (lane == 0) ws4[wv] = part;
        __syncthreads();
        if (tid == 0)
            out[0] = (ws4[0] + ws4[1] + ws4[2] + ws4[3]) * (1.0f / (float)NROWS);
    }
}

extern "C" void kernel_launch(void* const* d_in, const int* in_sizes, int n_in,
                              void* d_out, int out_size, void* d_ws, size_t ws_size,
                              hipStream_t stream) {
    const float* U = (const float*)d_in[0];
    const float* P = (const float*)d_in[1];
    float* out = (float*)d_out;
    char* ws = (char*)d_ws;
    // ws: Un bf16 (4 MB) | Pn bf16 (4 MB) | rowsum f32 (32 KB) | possim f32 (32 KB) | counter
    unsigned short* Un = (unsigned short*)ws;
    unsigned short* Pn = (unsigned short*)(ws + 4194304);
    float* rowsum = (float*)(ws + 8388608);
    float* possim = (float*)(ws + 8388608 + 32768);
    int* counter  = (int*)(ws + 8388608 + 65536);

    normalize_kernel<<<NROWS / 4, 256, 0, stream>>>(U, P, Un, Pn, possim, rowsum,
                                                    out, counter);
    sim_exp_rowsum<<<512, 256, 0, stream>>>(Un, Pn, rowsum, possim, counter, out);
}